// Round 14
// baseline (145.915 us; speedup 1.0000x reference)
//
#include <hip/hip_runtime.h>
#include <hip/hip_bf16.h>
#include <math.h>

#define BB 16
#define TT 2048
#define DD 1024
#define HH 64
#define QK_SCALE 0.18033688011112042f  // 0.125 * log2(e)  (exp2-domain softmax)

typedef short bf16x8 __attribute__((ext_vector_type(8)));
typedef short bf16x4 __attribute__((ext_vector_type(4)));
typedef float f32x4 __attribute__((ext_vector_type(4)));

__device__ __forceinline__ short f2bf(float f) {  // RNE (cold paths only)
  union { float f; unsigned u; } c; c.f = f;
  unsigned u = c.u + 0x7FFFu + ((c.u >> 16) & 1u);
  return (short)(u >> 16);
}

// packed pair f32x2 -> bf16x2 (v_cvt_pk_bf16_f32 via standard cast API)
__device__ __forceinline__ unsigned pk2(float lo, float hi) {
  float2 t; t.x = lo; t.y = hi;
  __hip_bfloat162 h = __float22bfloat162_rn(t);
  union { __hip_bfloat162 h; unsigned u; } c; c.h = h;
  return c.u;
}

// 64-col bf16 tile (128B row stride): XOR-swizzle 16B units by row&7.
__device__ __forceinline__ void* lds_swz(void* base, int row, int col) {
  int byte = (row << 7) + (col << 1);
  byte ^= (row & 7) << 4;
  return (void*)((char*)base + byte);
}

// ---------------------------------------------------------------------------
// Pack Wq|Wk|Wv (fp32 [D][H]) -> Wt bf16 [192][1024]
// ---------------------------------------------------------------------------
__global__ __launch_bounds__(256) void pack_wt(
    const float* __restrict__ Wq, const float* __restrict__ Wk,
    const float* __restrict__ Wv, short* __restrict__ wt) {
  const int idx = blockIdx.x * 256 + threadIdx.x;
  const int n = idx >> 7;
  const int k0 = (idx & 127) << 3;
  const float* W = (n < 64) ? Wq : (n < 128) ? Wk : Wv;
  const int h = n & 63;
  bf16x8 o;
#pragma unroll
  for (int j = 0; j < 8; ++j) o[j] = f2bf(W[(k0 + j) * HH + h]);
  *(bf16x8*)&wt[n * DD + k0] = o;
}

// ---------------------------------------------------------------------------
// QKV GEMM v5: WAVE-AUTONOMOUS, ZERO BARRIERS.
// Each wave owns 16 x-rows x 96 W-cols with a PRIVATE double-buffered LDS
// tile (16 rows x 72 shorts = 144B pad rows: read banks (q16+4kf+g)%8 are
// uniform, no XOR needed). No __syncthreads anywhere -> no vmcnt(0) barrier
// drain; only counted same-wave waitcnts -> loads span iterations, waves
// drift freely. 4096 waves, launch_bounds(256,4) for 16 waves/CU.
// Q pre-scaled by QK_SCALE; V written transposed to vt [b][h][t].
// ---------------------------------------------------------------------------
__global__ __launch_bounds__(256, 4) void qkv_mfma(
    const float* __restrict__ x, const short* __restrict__ wt,
    short* __restrict__ qo, short* __restrict__ ko, short* __restrict__ vt) {
  __shared__ short xls[4 * 2 * 16 * 72];  // 18 KB: 4 waves x 2 bufs x 16x72
  const int tid = threadIdx.x;
  const int lane = tid & 63;
  const int w = tid >> 6;
  const int q16 = lane & 15;
  const int g = lane >> 4;
  const int v = blockIdx.x * 4 + w;   // global wave id 0..4095
  const size_t r0 = (size_t)(v >> 1) * 16;  // 16-row tile
  const int ch = v & 1;                     // 96-col half

  const int srow = lane >> 2;         // staging row 0..15
  const int skseg = (lane & 3) << 4;  // k-offset 0,16,32,48 within K=64 step
  const float* xrow = x + (r0 + srow) * DD + skseg;

  short* wlds = xls + w * (2 * 16 * 72);
  const int woff = srow * 72 + ((lane & 3) << 4);  // write base (shorts)

  f32x4 acc[6];
#pragma unroll
  for (int nf = 0; nf < 6; ++nf) acc[nf] = (f32x4){0.f, 0.f, 0.f, 0.f};

  const short* wp[6];
#pragma unroll
  for (int nf = 0; nf < 6; ++nf)
    wp[nf] = wt + (size_t)(ch * 96 + nf * 16 + q16) * DD + g * 8;

  // prologue: stage tile 0 into buf 0
  {
    const float4* xp = (const float4*)xrow;
    float4 xa0 = xp[0], xa1 = xp[1], xa2 = xp[2], xa3 = xp[3];
    bf16x8 s0, s1;
    unsigned* u0 = (unsigned*)&s0;
    unsigned* u1 = (unsigned*)&s1;
    u0[0] = pk2(xa0.x, xa0.y); u0[1] = pk2(xa0.z, xa0.w);
    u0[2] = pk2(xa1.x, xa1.y); u0[3] = pk2(xa1.z, xa1.w);
    u1[0] = pk2(xa2.x, xa2.y); u1[1] = pk2(xa2.z, xa2.w);
    u1[2] = pk2(xa3.x, xa3.y); u1[3] = pk2(xa3.z, xa3.w);
    *(bf16x8*)&wlds[woff] = s0;
    *(bf16x8*)&wlds[woff + 8] = s1;
  }

  int cur = 0;
#pragma unroll 2
  for (int ks = 0; ks < 16; ++ks) {
    float4 xa0, xa1, xa2, xa3;
    if (ks < 15) {  // issue next tile's loads; completion awaited by counted
      const float4* xp = (const float4*)(xrow + (ks + 1) * 64);  // vmcnt only
      xa0 = xp[0]; xa1 = xp[1]; xa2 = xp[2]; xa3 = xp[3];
    }

#pragma unroll
    for (int kf = 0; kf < 2; ++kf) {
      const bf16x8 af =
          *(const bf16x8*)&wlds[cur * (16 * 72) + q16 * 72 + ((kf * 4 + g) << 3)];
      const int kb = ks * 64 + kf * 32;
#pragma unroll
      for (int nf = 0; nf < 6; ++nf) {
        bf16x8 bw = *(const bf16x8*)(wp[nf] + kb);
        acc[nf] = __builtin_amdgcn_mfma_f32_16x16x32_bf16(af, bw, acc[nf], 0, 0, 0);
      }
    }

    if (ks < 15) {
      bf16x8 s0, s1;
      unsigned* u0 = (unsigned*)&s0;
      unsigned* u1 = (unsigned*)&s1;
      u0[0] = pk2(xa0.x, xa0.y); u0[1] = pk2(xa0.z, xa0.w);
      u0[2] = pk2(xa1.x, xa1.y); u0[3] = pk2(xa1.z, xa1.w);
      u1[0] = pk2(xa2.x, xa2.y); u1[1] = pk2(xa2.z, xa2.w);
      u1[2] = pk2(xa3.x, xa3.y); u1[3] = pk2(xa3.z, xa3.w);
      const int wb = (cur ^ 1) * (16 * 72) + woff;
      *(bf16x8*)&wlds[wb] = s0;
      *(bf16x8*)&wlds[wb + 8] = s1;
      cur ^= 1;
    }
  }

  // epilogue: q/k row-major bf16 (Q pre-scaled); v transposed to vt [b][h][t]
#pragma unroll
  for (int nf = 0; nf < 6; ++nf) {
    const int ncol = ch * 96 + nf * 16;  // frag-uniform base
    const int mat = ncol >> 6;
    const int h = (ncol + q16) & 63;
    if (mat < 2) {
      short* outp = mat ? ko : qo;
      const float fac = mat ? 1.0f : QK_SCALE;
#pragma unroll
      for (int r = 0; r < 4; ++r)
        outp[(r0 + g * 4 + r) * HH + h] = f2bf(acc[nf][r] * fac);
    } else {
      const int bb = (int)(r0 >> 11);
      const int tloc = (int)(r0 & 2047) + g * 4;
      uint2 pkv;
      pkv.x = pk2(acc[nf][0], acc[nf][1]);
      pkv.y = pk2(acc[nf][2], acc[nf][3]);
      *(uint2*)&vt[((size_t)bb * HH + h) * TT + tloc] = pkv;
    }
  }
}

// ---------------------------------------------------------------------------
// Flash attention (identical to round 10 structure).
// ---------------------------------------------------------------------------
__global__ __launch_bounds__(256, 4) void attn_mfma(
    const short* __restrict__ q, const short* __restrict__ k,
    const short* __restrict__ vt, float* __restrict__ out) {
  __shared__ short klds[2][64 * 64];
  __shared__ short vlds[2][64 * 64];

  const int id = blockIdx.x;  // 0..511
  const int b = (id & 7) | (((id >> 3) & 1) << 3);
  const int kk = id >> 4;
  const int qt = (kk < 16) ? (31 - kk) : (kk - 16);
  const int t0 = qt << 6;
  const int tid = threadIdx.x;
  const int lane = tid & 63;
  const int w = tid >> 6;
  const int q16 = lane & 15;
  const int g = lane >> 4;
  const int NC = qt + 1;

  const size_t brow = (size_t)b * TT;
  const short* kg = k + brow * HH;
  const short* vtg = vt + (size_t)b * HH * TT;

  const int srow = tid >> 2;
  const int scol = (tid & 3) << 4;

  const int vgA = (scol >> 3) & 3;
  const int vgB = ((scol + 8) >> 3) & 3;
  const int vm2 = scol >> 5;
  const short* vrow_p = vtg + srow * TT + vm2 * 32;

  bf16x8 kr0 = *(const bf16x8*)&kg[srow * HH + scol];
  bf16x8 kr1 = *(const bf16x8*)&kg[srow * HH + scol + 8];
  bf16x4 va0 = *(const bf16x4*)(vrow_p + 4 * vgA);
  bf16x4 va1 = *(const bf16x4*)(vrow_p + 16 + 4 * vgA);
  bf16x4 vb0 = *(const bf16x4*)(vrow_p + 4 * vgB);
  bf16x4 vb1 = *(const bf16x4*)(vrow_p + 16 + 4 * vgB);

  {
    const short* qsrc = q + (brow + t0 + srow) * HH;
    *(bf16x8*)lds_swz(klds[0], srow, scol) = *(const bf16x8*)&qsrc[scol];
    *(bf16x8*)lds_swz(klds[0], srow, scol + 8) = *(const bf16x8*)&qsrc[scol + 8];
  }
  __syncthreads();
  bf16x8 qa[2];
#pragma unroll
  for (int kf = 0; kf < 2; ++kf)
    qa[kf] = *(bf16x8*)lds_swz(klds[0], w * 16 + q16, kf * 32 + g * 8);
  __syncthreads();

  *(bf16x8*)lds_swz(klds[0], srow, scol) = kr0;
  *(bf16x8*)lds_swz(klds[0], srow, scol + 8) = kr1;
  *(bf16x8*)lds_swz(vlds[0], srow, scol) =
      __builtin_shufflevector(va0, va1, 0, 1, 2, 3, 4, 5, 6, 7);
  *(bf16x8*)lds_swz(vlds[0], srow, scol + 8) =
      __builtin_shufflevector(vb0, vb1, 0, 1, 2, 3, 4, 5, 6, 7);
  __syncthreads();

  f32x4 po[4];
  f32x4 lacc = (f32x4){0.f, 0.f, 0.f, 0.f};
  float m = -INFINITY;
#pragma unroll
  for (int nf = 0; nf < 4; ++nf) po[nf] = (f32x4){0.f, 0.f, 0.f, 0.f};

  const bf16x8 ones = {0x3F80, 0x3F80, 0x3F80, 0x3F80,
                       0x3F80, 0x3F80, 0x3F80, 0x3F80};
  int cur = 0;

  for (int c = 0; c < NC; ++c) {
    const bool notlast = (c + 1 < NC);
    if (notlast) {
      const int s1 = (c + 1) << 6;
      kr0 = *(const bf16x8*)&kg[(s1 + srow) * HH + scol];
      kr1 = *(const bf16x8*)&kg[(s1 + srow) * HH + scol + 8];
      va0 = *(const bf16x4*)(vrow_p + s1 + 4 * vgA);
      va1 = *(const bf16x4*)(vrow_p + s1 + 16 + 4 * vgA);
      vb0 = *(const bf16x4*)(vrow_p + s1 + 4 * vgB);
      vb1 = *(const bf16x4*)(vrow_p + s1 + 16 + 4 * vgB);
    }

    f32x4 sfr[4];
#pragma unroll
    for (int nf = 0; nf < 4; ++nf) sfr[nf] = (f32x4){0.f, 0.f, 0.f, 0.f};
    __builtin_amdgcn_s_setprio(1);
#pragma unroll
    for (int nf = 0; nf < 4; ++nf)
#pragma unroll
      for (int kf = 0; kf < 2; ++kf) {
        bf16x8 kb = *(bf16x8*)lds_swz(klds[cur], nf * 16 + q16, kf * 32 + g * 8);
        sfr[nf] = __builtin_amdgcn_mfma_f32_16x16x32_bf16(kb, qa[kf], sfr[nf], 0, 0, 0);
      }
    __builtin_amdgcn_s_setprio(0);

    if (c == NC - 1) {
      const int qloc = w * 16 + q16;
#pragma unroll
      for (int nf = 0; nf < 4; ++nf)
#pragma unroll
        for (int r = 0; r < 4; ++r)
          if (16 * nf + 4 * g + r > qloc) sfr[nf][r] = -INFINITY;
    }

    float pm;
    {
      f32x4 t01 = (f32x4){fmaxf(sfr[0][0], sfr[1][0]), fmaxf(sfr[0][1], sfr[1][1]),
                          fmaxf(sfr[0][2], sfr[1][2]), fmaxf(sfr[0][3], sfr[1][3])};
      f32x4 t23 = (f32x4){fmaxf(sfr[2][0], sfr[3][0]), fmaxf(sfr[2][1], sfr[3][1]),
                          fmaxf(sfr[2][2], sfr[3][2]), fmaxf(sfr[2][3], sfr[3][3])};
      pm = fmaxf(fmaxf(fmaxf(t01[0], t23[0]), fmaxf(t01[1], t23[1])),
                 fmaxf(fmaxf(t01[2], t23[2]), fmaxf(t01[3], t23[3])));
      pm = fmaxf(pm, __shfl_xor(pm, 16));
      pm = fmaxf(pm, __shfl_xor(pm, 32));
    }

    if (__any(pm - m > 8.f)) {
      const float mn = fmaxf(m, pm);
      const float corr = exp2f(m - mn);
      m = mn;
      const int sbase = (lane & 48) + ((lane >> 4) << 2);
#pragma unroll
      for (int r = 0; r < 4; ++r) {
        const float cr = __shfl(corr, sbase + r);
        lacc[r] *= cr;
#pragma unroll
        for (int nf = 0; nf < 4; ++nf) po[nf][r] *= cr;
      }
    }

    bf16x8 pa[2];
#pragma unroll
    for (int m2 = 0; m2 < 2; ++m2) {
      float e0 = exp2f(sfr[2 * m2][0] - m), e1 = exp2f(sfr[2 * m2][1] - m);
      float e2 = exp2f(sfr[2 * m2][2] - m), e3 = exp2f(sfr[2 * m2][3] - m);
      float e4 = exp2f(sfr[2 * m2 + 1][0] - m), e5 = exp2f(sfr[2 * m2 + 1][1] - m);
      float e6 = exp2f(sfr[2 * m2 + 1][2] - m), e7 = exp2f(sfr[2 * m2 + 1][3] - m);
      unsigned* up = (unsigned*)&pa[m2];
      up[0] = pk2(e0, e1); up[1] = pk2(e2, e3);
      up[2] = pk2(e4, e5); up[3] = pk2(e6, e7);
    }

    __builtin_amdgcn_s_setprio(1);
#pragma unroll
    for (int m2 = 0; m2 < 2; ++m2) {
#pragma unroll
      for (int nf = 0; nf < 4; ++nf) {
        bf16x8 vb = *(bf16x8*)lds_swz(vlds[cur], nf * 16 + q16, m2 * 32 + g * 8);
        po[nf] = __builtin_amdgcn_mfma_f32_16x16x32_bf16(pa[m2], vb, po[nf], 0, 0, 0);
      }
      lacc = __builtin_amdgcn_mfma_f32_16x16x32_bf16(pa[m2], ones, lacc, 0, 0, 0);
    }
    __builtin_amdgcn_s_setprio(0);

    if (notlast) {
      *(bf16x8*)lds_swz(klds[cur ^ 1], srow, scol) = kr0;
      *(bf16x8*)lds_swz(klds[cur ^ 1], srow, scol + 8) = kr1;
      *(bf16x8*)lds_swz(vlds[cur ^ 1], srow, scol) =
          __builtin_shufflevector(va0, va1, 0, 1, 2, 3, 4, 5, 6, 7);
      *(bf16x8*)lds_swz(vlds[cur ^ 1], srow, scol + 8) =
          __builtin_shufflevector(vb0, vb1, 0, 1, 2, 3, 4, 5, 6, 7);
      __syncthreads();
      cur ^= 1;
    }
  }

  const int qrow = t0 + w * 16 + g * 4;
#pragma unroll
  for (int nf = 0; nf < 4; ++nf) {
    const int h = nf * 16 + q16;
#pragma unroll
    for (int r = 0; r < 4; ++r)
      out[(brow + qrow + r) * HH + h] = po[nf][r] / lacc[r];
  }
}

extern "C" void kernel_launch(void* const* d_in, const int* in_sizes, int n_in,
                              void* d_out, int out_size, void* d_ws, size_t ws_size,
                              hipStream_t stream) {
  const float* x  = (const float*)d_in[0];
  const float* Wq = (const float*)d_in[1];
  const float* Wk = (const float*)d_in[2];
  const float* Wv = (const float*)d_in[3];
  float* out = (float*)d_out;

  const size_t bth = (size_t)BB * TT * HH;  // 2,097,152
  short* qb  = (short*)d_ws;
  short* kb  = qb + bth;
  short* vtb = kb + bth;
  short* wtb = vtb + bth;  // 192*1024 bf16

  pack_wt<<<96, 256, 0, stream>>>(Wq, Wk, Wv, wtb);
  qkv_mfma<<<1024, 256, 0, stream>>>(x, wtb, qb, kb, vtb);
  attn_mfma<<<512, 256, 0, stream>>>(qb, kb, vtb, out);
}

// Round 15
// 90.010 us; speedup vs baseline: 1.6211x; 1.6211x over previous
//
#include <hip/hip_runtime.h>
#include <hip/hip_bf16.h>
#include <math.h>

#define BB 16
#define TT 2048
#define DD 1024
#define HH 64
#define QK_SCALE 0.18033688011112042f  // 0.125 * log2(e)  (exp2-domain softmax)

typedef short bf16x8 __attribute__((ext_vector_type(8)));
typedef short bf16x4 __attribute__((ext_vector_type(4)));
typedef float f32x4 __attribute__((ext_vector_type(4)));

__device__ __forceinline__ short f2bf(float f) {  // RNE (cold paths only)
  union { float f; unsigned u; } c; c.f = f;
  unsigned u = c.u + 0x7FFFu + ((c.u >> 16) & 1u);
  return (short)(u >> 16);
}

// packed pair f32x2 -> bf16x2 (v_cvt_pk_bf16_f32 via standard cast API)
__device__ __forceinline__ unsigned pk2(float lo, float hi) {
  float2 t; t.x = lo; t.y = hi;
  __hip_bfloat162 h = __float22bfloat162_rn(t);
  union { __hip_bfloat162 h; unsigned u; } c; c.h = h;
  return c.u;
}

// 64-col bf16 tile (128B row stride): XOR-swizzle 16B units by row&7.
__device__ __forceinline__ void* lds_swz(void* base, int row, int col) {
  int byte = (row << 7) + (col << 1);
  byte ^= (row & 7) << 4;
  return (void*)((char*)base + byte);
}

// ---------------------------------------------------------------------------
// Pack Wq|Wk|Wv (fp32 [D][H]) -> Wt bf16 [192][1024]
// ---------------------------------------------------------------------------
__global__ __launch_bounds__(256) void pack_wt(
    const float* __restrict__ Wq, const float* __restrict__ Wk,
    const float* __restrict__ Wv, short* __restrict__ wt) {
  const int idx = blockIdx.x * 256 + threadIdx.x;
  const int n = idx >> 7;
  const int k0 = (idx & 127) << 3;
  const float* W = (n < 64) ? Wq : (n < 128) ? Wk : Wv;
  const int h = n & 63;
  bf16x8 o;
#pragma unroll
  for (int j = 0; j < 8; ++j) o[j] = f2bf(W[(k0 + j) * HH + h]);
  *(bf16x8*)&wt[n * DD + k0] = o;
}

// ---------------------------------------------------------------------------
// QKV GEMM v6 = v2 structure + issue-order fix + VGPR diet.
// Per k-step: (1) W-frags loaded FIRST (L2) -> MFMA waits only vmcnt(4);
// (2) then issue next x-tile HBM loads (awaited after the MFMA burst, at
// pack time); (3) ds_read A-frags; (4) 24 MFMA; (5) pack+ds_write; barrier.
// No depth-2 xa, no W double-buffer regs -> ~115 VGPR, launch_bounds(256,4)
// = 4 blocks/CU: 4 independent barrier-groups overlap each other's stalls.
// Q pre-scaled by QK_SCALE; V written transposed to vt [b][h][t].
// ---------------------------------------------------------------------------
__global__ __launch_bounds__(256, 4) void qkv_mfma(
    const float* __restrict__ x, const short* __restrict__ wt,
    short* __restrict__ qo, short* __restrict__ ko, short* __restrict__ vt) {
  __shared__ short xs[2][64 * 64];  // 16 KB
  const int tid = threadIdx.x;
  const int lane = tid & 63;
  const int w = tid >> 6;
  const int q16 = lane & 15;
  const int g = lane >> 4;
  const size_t r0 = (size_t)blockIdx.x * 64;

  const int srow = tid >> 2;
  const int sc = (tid & 3) << 4;
  const float* xrow = x + (r0 + srow) * DD + sc;

  f32x4 acc[4][3];
#pragma unroll
  for (int mf = 0; mf < 4; ++mf)
#pragma unroll
    for (int nf = 0; nf < 3; ++nf) acc[mf][nf] = (f32x4){0.f, 0.f, 0.f, 0.f};

  const short* wp[3];
#pragma unroll
  for (int nf = 0; nf < 3; ++nf)
    wp[nf] = wt + (size_t)(w * 48 + nf * 16 + q16) * DD + g * 8;

  // prologue: x(0) -> regs -> pack -> xs[0]
  {
    const float4* xp = (const float4*)xrow;
    float4 a0 = xp[0], a1 = xp[1], a2 = xp[2], a3 = xp[3];
    bf16x8 s0, s1;
    unsigned* u0 = (unsigned*)&s0;
    unsigned* u1 = (unsigned*)&s1;
    u0[0] = pk2(a0.x, a0.y); u0[1] = pk2(a0.z, a0.w);
    u0[2] = pk2(a1.x, a1.y); u0[3] = pk2(a1.z, a1.w);
    u1[0] = pk2(a2.x, a2.y); u1[1] = pk2(a2.z, a2.w);
    u1[2] = pk2(a3.x, a3.y); u1[3] = pk2(a3.z, a3.w);
    *(bf16x8*)lds_swz(xs[0], srow, sc) = s0;
    *(bf16x8*)lds_swz(xs[0], srow, sc + 8) = s1;
  }
  __syncthreads();

  int cur = 0;
  for (int ks = 0; ks < 16; ++ks) {
    // (1) W-frags for THIS k-step, issued before x so MFMA waits vmcnt(4)
    bf16x8 bw[3][2];
#pragma unroll
    for (int nf = 0; nf < 3; ++nf)
#pragma unroll
      for (int kf = 0; kf < 2; ++kf)
        bw[nf][kf] = *(const bf16x8*)(wp[nf] + (ks << 6) + kf * 32);

    // (2) next x-tile: issue now, consumed only at pack time (after MFMAs)
    float4 a0, a1, a2, a3;
    if (ks < 15) {
      const float4* xp = (const float4*)(xrow + ((ks + 1) << 6));
      a0 = xp[0]; a1 = xp[1]; a2 = xp[2]; a3 = xp[3];
    }

    // (3) A-frags from LDS
    bf16x8 afr[4][2];
#pragma unroll
    for (int mf = 0; mf < 4; ++mf)
#pragma unroll
      for (int kf = 0; kf < 2; ++kf)
        afr[mf][kf] = *(bf16x8*)lds_swz(xs[cur], mf * 16 + q16, kf * 32 + g * 8);

    // (4) MFMA burst
#pragma unroll
    for (int mf = 0; mf < 4; ++mf)
#pragma unroll
      for (int nf = 0; nf < 3; ++nf)
#pragma unroll
        for (int kf = 0; kf < 2; ++kf)
          acc[mf][nf] = __builtin_amdgcn_mfma_f32_16x16x32_bf16(
              afr[mf][kf], bw[nf][kf], acc[mf][nf], 0, 0, 0);

    // (5) pack next tile, single barrier
    if (ks < 15) {
      bf16x8 s0, s1;
      unsigned* u0 = (unsigned*)&s0;
      unsigned* u1 = (unsigned*)&s1;
      u0[0] = pk2(a0.x, a0.y); u0[1] = pk2(a0.z, a0.w);
      u0[2] = pk2(a1.x, a1.y); u0[3] = pk2(a1.z, a1.w);
      u1[0] = pk2(a2.x, a2.y); u1[1] = pk2(a2.z, a2.w);
      u1[2] = pk2(a3.x, a3.y); u1[3] = pk2(a3.z, a3.w);
      *(bf16x8*)lds_swz(xs[cur ^ 1], srow, sc) = s0;
      *(bf16x8*)lds_swz(xs[cur ^ 1], srow, sc + 8) = s1;
      __syncthreads();
      cur ^= 1;
    }
  }

  // epilogue: q/k row-major bf16 (Q pre-scaled); v transposed to vt [b][h][t]
#pragma unroll
  for (int nf = 0; nf < 3; ++nf) {
    const int n = w * 48 + nf * 16 + q16;
    const int mat = n >> 6;  // frag-uniform
    const int h = n & 63;
    if (mat < 2) {
      short* outp = mat ? ko : qo;
      const float fac = mat ? 1.0f : QK_SCALE;
#pragma unroll
      for (int mf = 0; mf < 4; ++mf)
#pragma unroll
        for (int r = 0; r < 4; ++r)
          outp[(r0 + mf * 16 + g * 4 + r) * HH + h] = f2bf(acc[mf][nf][r] * fac);
    } else {
      const int bb = (int)(r0 >> 11);
      const int tloc = (int)(r0 & 2047);
#pragma unroll
      for (int mf = 0; mf < 4; ++mf) {
        uint2 pkv;
        pkv.x = pk2(acc[mf][nf][0], acc[mf][nf][1]);
        pkv.y = pk2(acc[mf][nf][2], acc[mf][nf][3]);
        *(uint2*)&vt[((size_t)bb * HH + h) * TT + tloc + mf * 16 + g * 4] = pkv;
      }
    }
  }
}

// ---------------------------------------------------------------------------
// Flash attention (identical to round 10 structure).
// ---------------------------------------------------------------------------
__global__ __launch_bounds__(256, 4) void attn_mfma(
    const short* __restrict__ q, const short* __restrict__ k,
    const short* __restrict__ vt, float* __restrict__ out) {
  __shared__ short klds[2][64 * 64];
  __shared__ short vlds[2][64 * 64];

  const int id = blockIdx.x;  // 0..511
  const int b = (id & 7) | (((id >> 3) & 1) << 3);
  const int kk = id >> 4;
  const int qt = (kk < 16) ? (31 - kk) : (kk - 16);
  const int t0 = qt << 6;
  const int tid = threadIdx.x;
  const int lane = tid & 63;
  const int w = tid >> 6;
  const int q16 = lane & 15;
  const int g = lane >> 4;
  const int NC = qt + 1;

  const size_t brow = (size_t)b * TT;
  const short* kg = k + brow * HH;
  const short* vtg = vt + (size_t)b * HH * TT;

  const int srow = tid >> 2;
  const int scol = (tid & 3) << 4;

  const int vgA = (scol >> 3) & 3;
  const int vgB = ((scol + 8) >> 3) & 3;
  const int vm2 = scol >> 5;
  const short* vrow_p = vtg + srow * TT + vm2 * 32;

  bf16x8 kr0 = *(const bf16x8*)&kg[srow * HH + scol];
  bf16x8 kr1 = *(const bf16x8*)&kg[srow * HH + scol + 8];
  bf16x4 va0 = *(const bf16x4*)(vrow_p + 4 * vgA);
  bf16x4 va1 = *(const bf16x4*)(vrow_p + 16 + 4 * vgA);
  bf16x4 vb0 = *(const bf16x4*)(vrow_p + 4 * vgB);
  bf16x4 vb1 = *(const bf16x4*)(vrow_p + 16 + 4 * vgB);

  {
    const short* qsrc = q + (brow + t0 + srow) * HH;
    *(bf16x8*)lds_swz(klds[0], srow, scol) = *(const bf16x8*)&qsrc[scol];
    *(bf16x8*)lds_swz(klds[0], srow, scol + 8) = *(const bf16x8*)&qsrc[scol + 8];
  }
  __syncthreads();
  bf16x8 qa[2];
#pragma unroll
  for (int kf = 0; kf < 2; ++kf)
    qa[kf] = *(bf16x8*)lds_swz(klds[0], w * 16 + q16, kf * 32 + g * 8);
  __syncthreads();

  *(bf16x8*)lds_swz(klds[0], srow, scol) = kr0;
  *(bf16x8*)lds_swz(klds[0], srow, scol + 8) = kr1;
  *(bf16x8*)lds_swz(vlds[0], srow, scol) =
      __builtin_shufflevector(va0, va1, 0, 1, 2, 3, 4, 5, 6, 7);
  *(bf16x8*)lds_swz(vlds[0], srow, scol + 8) =
      __builtin_shufflevector(vb0, vb1, 0, 1, 2, 3, 4, 5, 6, 7);
  __syncthreads();

  f32x4 po[4];
  f32x4 lacc = (f32x4){0.f, 0.f, 0.f, 0.f};
  float m = -INFINITY;
#pragma unroll
  for (int nf = 0; nf < 4; ++nf) po[nf] = (f32x4){0.f, 0.f, 0.f, 0.f};

  const bf16x8 ones = {0x3F80, 0x3F80, 0x3F80, 0x3F80,
                       0x3F80, 0x3F80, 0x3F80, 0x3F80};
  int cur = 0;

  for (int c = 0; c < NC; ++c) {
    const bool notlast = (c + 1 < NC);
    if (notlast) {
      const int s1 = (c + 1) << 6;
      kr0 = *(const bf16x8*)&kg[(s1 + srow) * HH + scol];
      kr1 = *(const bf16x8*)&kg[(s1 + srow) * HH + scol + 8];
      va0 = *(const bf16x4*)(vrow_p + s1 + 4 * vgA);
      va1 = *(const bf16x4*)(vrow_p + s1 + 16 + 4 * vgA);
      vb0 = *(const bf16x4*)(vrow_p + s1 + 4 * vgB);
      vb1 = *(const bf16x4*)(vrow_p + s1 + 16 + 4 * vgB);
    }

    f32x4 sfr[4];
#pragma unroll
    for (int nf = 0; nf < 4; ++nf) sfr[nf] = (f32x4){0.f, 0.f, 0.f, 0.f};
    __builtin_amdgcn_s_setprio(1);
#pragma unroll
    for (int nf = 0; nf < 4; ++nf)
#pragma unroll
      for (int kf = 0; kf < 2; ++kf) {
        bf16x8 kb = *(bf16x8*)lds_swz(klds[cur], nf * 16 + q16, kf * 32 + g * 8);
        sfr[nf] = __builtin_amdgcn_mfma_f32_16x16x32_bf16(kb, qa[kf], sfr[nf], 0, 0, 0);
      }
    __builtin_amdgcn_s_setprio(0);

    if (c == NC - 1) {
      const int qloc = w * 16 + q16;
#pragma unroll
      for (int nf = 0; nf < 4; ++nf)
#pragma unroll
        for (int r = 0; r < 4; ++r)
          if (16 * nf + 4 * g + r > qloc) sfr[nf][r] = -INFINITY;
    }

    float pm;
    {
      f32x4 t01 = (f32x4){fmaxf(sfr[0][0], sfr[1][0]), fmaxf(sfr[0][1], sfr[1][1]),
                          fmaxf(sfr[0][2], sfr[1][2]), fmaxf(sfr[0][3], sfr[1][3])};
      f32x4 t23 = (f32x4){fmaxf(sfr[2][0], sfr[3][0]), fmaxf(sfr[2][1], sfr[3][1]),
                          fmaxf(sfr[2][2], sfr[3][2]), fmaxf(sfr[2][3], sfr[3][3])};
      pm = fmaxf(fmaxf(fmaxf(t01[0], t23[0]), fmaxf(t01[1], t23[1])),
                 fmaxf(fmaxf(t01[2], t23[2]), fmaxf(t01[3], t23[3])));
      pm = fmaxf(pm, __shfl_xor(pm, 16));
      pm = fmaxf(pm, __shfl_xor(pm, 32));
    }

    if (__any(pm - m > 8.f)) {
      const float mn = fmaxf(m, pm);
      const float corr = exp2f(m - mn);
      m = mn;
      const int sbase = (lane & 48) + ((lane >> 4) << 2);
#pragma unroll
      for (int r = 0; r < 4; ++r) {
        const float cr = __shfl(corr, sbase + r);
        lacc[r] *= cr;
#pragma unroll
        for (int nf = 0; nf < 4; ++nf) po[nf][r] *= cr;
      }
    }

    bf16x8 pa[2];
#pragma unroll
    for (int m2 = 0; m2 < 2; ++m2) {
      float e0 = exp2f(sfr[2 * m2][0] - m), e1 = exp2f(sfr[2 * m2][1] - m);
      float e2 = exp2f(sfr[2 * m2][2] - m), e3 = exp2f(sfr[2 * m2][3] - m);
      float e4 = exp2f(sfr[2 * m2 + 1][0] - m), e5 = exp2f(sfr[2 * m2 + 1][1] - m);
      float e6 = exp2f(sfr[2 * m2 + 1][2] - m), e7 = exp2f(sfr[2 * m2 + 1][3] - m);
      unsigned* up = (unsigned*)&pa[m2];
      up[0] = pk2(e0, e1); up[1] = pk2(e2, e3);
      up[2] = pk2(e4, e5); up[3] = pk2(e6, e7);
    }

    __builtin_amdgcn_s_setprio(1);
#pragma unroll
    for (int m2 = 0; m2 < 2; ++m2) {
#pragma unroll
      for (int nf = 0; nf < 4; ++nf) {
        bf16x8 vb = *(bf16x8*)lds_swz(vlds[cur], nf * 16 + q16, m2 * 32 + g * 8);
        po[nf] = __builtin_amdgcn_mfma_f32_16x16x32_bf16(pa[m2], vb, po[nf], 0, 0, 0);
      }
      lacc = __builtin_amdgcn_mfma_f32_16x16x32_bf16(pa[m2], ones, lacc, 0, 0, 0);
    }
    __builtin_amdgcn_s_setprio(0);

    if (notlast) {
      *(bf16x8*)lds_swz(klds[cur ^ 1], srow, scol) = kr0;
      *(bf16x8*)lds_swz(klds[cur ^ 1], srow, scol + 8) = kr1;
      *(bf16x8*)lds_swz(vlds[cur ^ 1], srow, scol) =
          __builtin_shufflevector(va0, va1, 0, 1, 2, 3, 4, 5, 6, 7);
      *(bf16x8*)lds_swz(vlds[cur ^ 1], srow, scol + 8) =
          __builtin_shufflevector(vb0, vb1, 0, 1, 2, 3, 4, 5, 6, 7);
      __syncthreads();
      cur ^= 1;
    }
  }

  const int qrow = t0 + w * 16 + g * 4;
#pragma unroll
  for (int nf = 0; nf < 4; ++nf) {
    const int h = nf * 16 + q16;
#pragma unroll
    for (int r = 0; r < 4; ++r)
      out[(brow + qrow + r) * HH + h] = po[nf][r] / lacc[r];
  }
}

extern "C" void kernel_launch(void* const* d_in, const int* in_sizes, int n_in,
                              void* d_out, int out_size, void* d_ws, size_t ws_size,
                              hipStream_t stream) {
  const float* x  = (const float*)d_in[0];
  const float* Wq = (const float*)d_in[1];
  const float* Wk = (const float*)d_in[2];
  const float* Wv = (const float*)d_in[3];
  float* out = (float*)d_out;

  const size_t bth = (size_t)BB * TT * HH;  // 2,097,152
  short* qb  = (short*)d_ws;
  short* kb  = qb + bth;
  short* vtb = kb + bth;
  short* wtb = vtb + bth;  // 192*1024 bf16

  pack_wt<<<96, 256, 0, stream>>>(Wq, Wk, Wv, wtb);
  qkv_mfma<<<(BB * TT) / 64, 256, 0, stream>>>(x, wtb, qb, kb, vtb);
  attn_mfma<<<512, 256, 0, stream>>>(qb, kb, vtb, out);
}

// Round 16
// 81.791 us; speedup vs baseline: 1.7840x; 1.1005x over previous
//
#include <hip/hip_runtime.h>
#include <hip/hip_bf16.h>
#include <math.h>

#define BB 16
#define TT 2048
#define DD 1024
#define HH 64
#define QK_SCALE 0.18033688011112042f  // 0.125 * log2(e)  (exp2-domain softmax)

typedef short bf16x8 __attribute__((ext_vector_type(8)));
typedef short bf16x4 __attribute__((ext_vector_type(4)));
typedef float f32x4 __attribute__((ext_vector_type(4)));

__device__ __forceinline__ short f2bf(float f) {  // RNE (cold paths only)
  union { float f; unsigned u; } c; c.f = f;
  unsigned u = c.u + 0x7FFFu + ((c.u >> 16) & 1u);
  return (short)(u >> 16);
}

// packed pair f32x2 -> bf16x2 (v_cvt_pk_bf16_f32 via standard cast API)
__device__ __forceinline__ unsigned pk2(float lo, float hi) {
  float2 t; t.x = lo; t.y = hi;
  __hip_bfloat162 h = __float22bfloat162_rn(t);
  union { __hip_bfloat162 h; unsigned u; } c; c.h = h;
  return c.u;
}

// T4 barrier (m201/HK pattern): drain ONLY lgkmcnt before s_barrier, so
// in-flight global loads (vmcnt) survive across the barrier. __syncthreads
// would emit s_waitcnt vmcnt(0) lgkmcnt(0) and kill all prefetch depth.
__device__ __forceinline__ void barrier_lds_only() {
  asm volatile("s_waitcnt lgkmcnt(0)" ::: "memory");
  __builtin_amdgcn_sched_barrier(0);  // rule #18: pin code after the waitcnt
  __builtin_amdgcn_s_barrier();
}

// 64-col bf16 tile (128B row stride): XOR-swizzle 16B units by row&7.
__device__ __forceinline__ void* lds_swz(void* base, int row, int col) {
  int byte = (row << 7) + (col << 1);
  byte ^= (row & 7) << 4;
  return (void*)((char*)base + byte);
}

// ---------------------------------------------------------------------------
// Pack Wq|Wk|Wv (fp32 [D][H]) -> Wt bf16 [192][1024]
// ---------------------------------------------------------------------------
__global__ __launch_bounds__(256) void pack_wt(
    const float* __restrict__ Wq, const float* __restrict__ Wk,
    const float* __restrict__ Wv, short* __restrict__ wt) {
  const int idx = blockIdx.x * 256 + threadIdx.x;
  const int n = idx >> 7;
  const int k0 = (idx & 127) << 3;
  const float* W = (n < 64) ? Wq : (n < 128) ? Wk : Wv;
  const int h = n & 63;
  bf16x8 o;
#pragma unroll
  for (int j = 0; j < 8; ++j) o[j] = f2bf(W[(k0 + j) * HH + h]);
  *(bf16x8*)&wt[n * DD + k0] = o;
}

// ---------------------------------------------------------------------------
// QKV GEMM = round-10 v2 (best known) with ONE change: in-loop barrier is
// barrier_lds_only() -> depth-2 x prefetch + bnxt W prefetch actually span
// iterations (counted vmcnt instead of vmcnt(0) drain).
// ---------------------------------------------------------------------------
__global__ __launch_bounds__(256) void qkv_mfma(
    const float* __restrict__ x, const short* __restrict__ wt,
    short* __restrict__ qo, short* __restrict__ ko, short* __restrict__ vt) {
  __shared__ short xs[2][64 * 64];
  const int tid = threadIdx.x;
  const int lane = tid & 63;
  const int w = tid >> 6;
  const int q16 = lane & 15;
  const int g = lane >> 4;
  const size_t r0 = (size_t)blockIdx.x * 64;

  const int srow = tid >> 2;
  const int sc = (tid & 3) << 4;
  const float* xrow = x + (r0 + srow) * DD + sc;

  f32x4 acc[4][3];
#pragma unroll
  for (int mf = 0; mf < 4; ++mf)
#pragma unroll
    for (int nf = 0; nf < 3; ++nf) acc[mf][nf] = (f32x4){0.f, 0.f, 0.f, 0.f};

  const short* wp[3];
#pragma unroll
  for (int nf = 0; nf < 3; ++nf)
    wp[nf] = wt + (size_t)(w * 48 + nf * 16 + q16) * DD + g * 8;

  float4 xa[2][4];  // two in-flight x reg-sets (unroll-2 keeps idx static)
  {
    const float4* xp = (const float4*)xrow;
#pragma unroll
    for (int j = 0; j < 4; ++j) xa[0][j] = xp[j];
    bf16x8 s0, s1;
    unsigned* u0 = (unsigned*)&s0;
    unsigned* u1 = (unsigned*)&s1;
    u0[0] = pk2(xa[0][0].x, xa[0][0].y); u0[1] = pk2(xa[0][0].z, xa[0][0].w);
    u0[2] = pk2(xa[0][1].x, xa[0][1].y); u0[3] = pk2(xa[0][1].z, xa[0][1].w);
    u1[0] = pk2(xa[0][2].x, xa[0][2].y); u1[1] = pk2(xa[0][2].z, xa[0][2].w);
    u1[2] = pk2(xa[0][3].x, xa[0][3].y); u1[3] = pk2(xa[0][3].z, xa[0][3].w);
    *(bf16x8*)lds_swz(xs[0], srow, sc) = s0;
    *(bf16x8*)lds_swz(xs[0], srow, sc + 8) = s1;
    const float4* xp1 = (const float4*)(xrow + 64);
#pragma unroll
    for (int j = 0; j < 4; ++j) xa[1][j] = xp1[j];
  }
  bf16x8 bcur[3][2];
#pragma unroll
  for (int nf = 0; nf < 3; ++nf)
#pragma unroll
    for (int kf = 0; kf < 2; ++kf)
      bcur[nf][kf] = *(const bf16x8*)(wp[nf] + kf * 32);
  __syncthreads();

  int cur = 0;
#pragma unroll 2
  for (int ks = 0; ks < 16; ++ks) {
    const int pnext = (ks + 1) & 1;  // set holding x(ks+1)
    const int pfree = ks & 1;        // set to refill with x(ks+2)
    if (ks < 14) {
      const float4* xp = (const float4*)(xrow + (ks + 2) * 64);
#pragma unroll
      for (int j = 0; j < 4; ++j) xa[pfree][j] = xp[j];
    }
    bf16x8 bnxt[3][2];
    if (ks < 15) {
      const int k1 = (ks + 1) << 6;
#pragma unroll
      for (int nf = 0; nf < 3; ++nf)
#pragma unroll
        for (int kf = 0; kf < 2; ++kf)
          bnxt[nf][kf] = *(const bf16x8*)(wp[nf] + k1 + kf * 32);
    }

    bf16x8 afr[4][2];
#pragma unroll
    for (int mf = 0; mf < 4; ++mf)
#pragma unroll
      for (int kf = 0; kf < 2; ++kf)
        afr[mf][kf] = *(bf16x8*)lds_swz(xs[cur], mf * 16 + q16, kf * 32 + g * 8);

#pragma unroll
    for (int mf = 0; mf < 4; ++mf)
#pragma unroll
      for (int nf = 0; nf < 3; ++nf)
#pragma unroll
        for (int kf = 0; kf < 2; ++kf)
          acc[mf][nf] = __builtin_amdgcn_mfma_f32_16x16x32_bf16(
              afr[mf][kf], bcur[nf][kf], acc[mf][nf], 0, 0, 0);

    if (ks < 15) {
      bf16x8 s0, s1;
      unsigned* u0 = (unsigned*)&s0;
      unsigned* u1 = (unsigned*)&s1;
      u0[0] = pk2(xa[pnext][0].x, xa[pnext][0].y);
      u0[1] = pk2(xa[pnext][0].z, xa[pnext][0].w);
      u0[2] = pk2(xa[pnext][1].x, xa[pnext][1].y);
      u0[3] = pk2(xa[pnext][1].z, xa[pnext][1].w);
      u1[0] = pk2(xa[pnext][2].x, xa[pnext][2].y);
      u1[1] = pk2(xa[pnext][2].z, xa[pnext][2].w);
      u1[2] = pk2(xa[pnext][3].x, xa[pnext][3].y);
      u1[3] = pk2(xa[pnext][3].z, xa[pnext][3].w);
      *(bf16x8*)lds_swz(xs[cur ^ 1], srow, sc) = s0;
      *(bf16x8*)lds_swz(xs[cur ^ 1], srow, sc + 8) = s1;
      barrier_lds_only();  // T4: x(k+2) loads stay in flight across this
      cur ^= 1;
#pragma unroll
      for (int nf = 0; nf < 3; ++nf)
#pragma unroll
        for (int kf = 0; kf < 2; ++kf) bcur[nf][kf] = bnxt[nf][kf];
    }
  }

#pragma unroll
  for (int nf = 0; nf < 3; ++nf) {
    const int n = w * 48 + nf * 16 + q16;
    const int mat = n >> 6;  // frag-uniform
    const int h = n & 63;
    if (mat < 2) {
      short* outp = mat ? ko : qo;
      const float fac = mat ? 1.0f : QK_SCALE;
#pragma unroll
      for (int mf = 0; mf < 4; ++mf)
#pragma unroll
        for (int r = 0; r < 4; ++r)
          outp[(r0 + mf * 16 + g * 4 + r) * HH + h] = f2bf(acc[mf][nf][r] * fac);
    } else {
      const int bb = (int)(r0 >> 11);
      const int tloc = (int)(r0 & 2047);
#pragma unroll
      for (int mf = 0; mf < 4; ++mf) {
        uint2 pkv;
        pkv.x = pk2(acc[mf][nf][0], acc[mf][nf][1]);
        pkv.y = pk2(acc[mf][nf][2], acc[mf][nf][3]);
        *(uint2*)&vt[((size_t)bb * HH + h) * TT + tloc + mf * 16 + g * 4] = pkv;
      }
    }
  }
}

// ---------------------------------------------------------------------------
// Flash attention = round-10 structure with the same T4 barrier swap:
// K/V prefetch loads for chunk c+1 stay in flight across the chunk barrier.
// ---------------------------------------------------------------------------
__global__ __launch_bounds__(256, 4) void attn_mfma(
    const short* __restrict__ q, const short* __restrict__ k,
    const short* __restrict__ vt, float* __restrict__ out) {
  __shared__ short klds[2][64 * 64];
  __shared__ short vlds[2][64 * 64];

  const int id = blockIdx.x;  // 0..511
  const int b = (id & 7) | (((id >> 3) & 1) << 3);
  const int kk = id >> 4;
  const int qt = (kk < 16) ? (31 - kk) : (kk - 16);
  const int t0 = qt << 6;
  const int tid = threadIdx.x;
  const int lane = tid & 63;
  const int w = tid >> 6;
  const int q16 = lane & 15;
  const int g = lane >> 4;
  const int NC = qt + 1;

  const size_t brow = (size_t)b * TT;
  const short* kg = k + brow * HH;
  const short* vtg = vt + (size_t)b * HH * TT;

  const int srow = tid >> 2;
  const int scol = (tid & 3) << 4;

  const int vgA = (scol >> 3) & 3;
  const int vgB = ((scol + 8) >> 3) & 3;
  const int vm2 = scol >> 5;
  const short* vrow_p = vtg + srow * TT + vm2 * 32;

  bf16x8 kr0 = *(const bf16x8*)&kg[srow * HH + scol];
  bf16x8 kr1 = *(const bf16x8*)&kg[srow * HH + scol + 8];
  bf16x4 va0 = *(const bf16x4*)(vrow_p + 4 * vgA);
  bf16x4 va1 = *(const bf16x4*)(vrow_p + 16 + 4 * vgA);
  bf16x4 vb0 = *(const bf16x4*)(vrow_p + 4 * vgB);
  bf16x4 vb1 = *(const bf16x4*)(vrow_p + 16 + 4 * vgB);

  {
    const short* qsrc = q + (brow + t0 + srow) * HH;
    *(bf16x8*)lds_swz(klds[0], srow, scol) = *(const bf16x8*)&qsrc[scol];
    *(bf16x8*)lds_swz(klds[0], srow, scol + 8) = *(const bf16x8*)&qsrc[scol + 8];
  }
  __syncthreads();
  bf16x8 qa[2];
#pragma unroll
  for (int kf = 0; kf < 2; ++kf)
    qa[kf] = *(bf16x8*)lds_swz(klds[0], w * 16 + q16, kf * 32 + g * 8);
  __syncthreads();

  *(bf16x8*)lds_swz(klds[0], srow, scol) = kr0;
  *(bf16x8*)lds_swz(klds[0], srow, scol + 8) = kr1;
  *(bf16x8*)lds_swz(vlds[0], srow, scol) =
      __builtin_shufflevector(va0, va1, 0, 1, 2, 3, 4, 5, 6, 7);
  *(bf16x8*)lds_swz(vlds[0], srow, scol + 8) =
      __builtin_shufflevector(vb0, vb1, 0, 1, 2, 3, 4, 5, 6, 7);
  __syncthreads();

  f32x4 po[4];
  f32x4 lacc = (f32x4){0.f, 0.f, 0.f, 0.f};
  float m = -INFINITY;
#pragma unroll
  for (int nf = 0; nf < 4; ++nf) po[nf] = (f32x4){0.f, 0.f, 0.f, 0.f};

  const bf16x8 ones = {0x3F80, 0x3F80, 0x3F80, 0x3F80,
                       0x3F80, 0x3F80, 0x3F80, 0x3F80};
  int cur = 0;

  for (int c = 0; c < NC; ++c) {
    const bool notlast = (c + 1 < NC);
    if (notlast) {
      const int s1 = (c + 1) << 6;
      kr0 = *(const bf16x8*)&kg[(s1 + srow) * HH + scol];
      kr1 = *(const bf16x8*)&kg[(s1 + srow) * HH + scol + 8];
      va0 = *(const bf16x4*)(vrow_p + s1 + 4 * vgA);
      va1 = *(const bf16x4*)(vrow_p + s1 + 16 + 4 * vgA);
      vb0 = *(const bf16x4*)(vrow_p + s1 + 4 * vgB);
      vb1 = *(const bf16x4*)(vrow_p + s1 + 16 + 4 * vgB);
    }

    f32x4 sfr[4];
#pragma unroll
    for (int nf = 0; nf < 4; ++nf) sfr[nf] = (f32x4){0.f, 0.f, 0.f, 0.f};
    __builtin_amdgcn_s_setprio(1);
#pragma unroll
    for (int nf = 0; nf < 4; ++nf)
#pragma unroll
      for (int kf = 0; kf < 2; ++kf) {
        bf16x8 kb = *(bf16x8*)lds_swz(klds[cur], nf * 16 + q16, kf * 32 + g * 8);
        sfr[nf] = __builtin_amdgcn_mfma_f32_16x16x32_bf16(kb, qa[kf], sfr[nf], 0, 0, 0);
      }
    __builtin_amdgcn_s_setprio(0);

    if (c == NC - 1) {
      const int qloc = w * 16 + q16;
#pragma unroll
      for (int nf = 0; nf < 4; ++nf)
#pragma unroll
        for (int r = 0; r < 4; ++r)
          if (16 * nf + 4 * g + r > qloc) sfr[nf][r] = -INFINITY;
    }

    float pm;
    {
      f32x4 t01 = (f32x4){fmaxf(sfr[0][0], sfr[1][0]), fmaxf(sfr[0][1], sfr[1][1]),
                          fmaxf(sfr[0][2], sfr[1][2]), fmaxf(sfr[0][3], sfr[1][3])};
      f32x4 t23 = (f32x4){fmaxf(sfr[2][0], sfr[3][0]), fmaxf(sfr[2][1], sfr[3][1]),
                          fmaxf(sfr[2][2], sfr[3][2]), fmaxf(sfr[2][3], sfr[3][3])};
      pm = fmaxf(fmaxf(fmaxf(t01[0], t23[0]), fmaxf(t01[1], t23[1])),
                 fmaxf(fmaxf(t01[2], t23[2]), fmaxf(t01[3], t23[3])));
      pm = fmaxf(pm, __shfl_xor(pm, 16));
      pm = fmaxf(pm, __shfl_xor(pm, 32));
    }

    if (__any(pm - m > 8.f)) {
      const float mn = fmaxf(m, pm);
      const float corr = exp2f(m - mn);
      m = mn;
      const int sbase = (lane & 48) + ((lane >> 4) << 2);
#pragma unroll
      for (int r = 0; r < 4; ++r) {
        const float cr = __shfl(corr, sbase + r);
        lacc[r] *= cr;
#pragma unroll
        for (int nf = 0; nf < 4; ++nf) po[nf][r] *= cr;
      }
    }

    bf16x8 pa[2];
#pragma unroll
    for (int m2 = 0; m2 < 2; ++m2) {
      float e0 = exp2f(sfr[2 * m2][0] - m), e1 = exp2f(sfr[2 * m2][1] - m);
      float e2 = exp2f(sfr[2 * m2][2] - m), e3 = exp2f(sfr[2 * m2][3] - m);
      float e4 = exp2f(sfr[2 * m2 + 1][0] - m), e5 = exp2f(sfr[2 * m2 + 1][1] - m);
      float e6 = exp2f(sfr[2 * m2 + 1][2] - m), e7 = exp2f(sfr[2 * m2 + 1][3] - m);
      unsigned* up = (unsigned*)&pa[m2];
      up[0] = pk2(e0, e1); up[1] = pk2(e2, e3);
      up[2] = pk2(e4, e5); up[3] = pk2(e6, e7);
    }

    __builtin_amdgcn_s_setprio(1);
#pragma unroll
    for (int m2 = 0; m2 < 2; ++m2) {
#pragma unroll
      for (int nf = 0; nf < 4; ++nf) {
        bf16x8 vb = *(bf16x8*)lds_swz(vlds[cur], nf * 16 + q16, m2 * 32 + g * 8);
        po[nf] = __builtin_amdgcn_mfma_f32_16x16x32_bf16(pa[m2], vb, po[nf], 0, 0, 0);
      }
      lacc = __builtin_amdgcn_mfma_f32_16x16x32_bf16(pa[m2], ones, lacc, 0, 0, 0);
    }
    __builtin_amdgcn_s_setprio(0);

    if (notlast) {
      barrier_lds_only();  // readers of chunk c done (K/V c+1 loads in flight)
      *(bf16x8*)lds_swz(klds[cur ^ 1], srow, scol) = kr0;
      *(bf16x8*)lds_swz(klds[cur ^ 1], srow, scol + 8) = kr1;
      *(bf16x8*)lds_swz(vlds[cur ^ 1], srow, scol) =
          __builtin_shufflevector(va0, va1, 0, 1, 2, 3, 4, 5, 6, 7);
      *(bf16x8*)lds_swz(vlds[cur ^ 1], srow, scol + 8) =
          __builtin_shufflevector(vb0, vb1, 0, 1, 2, 3, 4, 5, 6, 7);
      barrier_lds_only();  // staging visible to all waves
      cur ^= 1;
    }
  }

  const int qrow = t0 + w * 16 + g * 4;
#pragma unroll
  for (int nf = 0; nf < 4; ++nf) {
    const int h = nf * 16 + q16;
#pragma unroll
    for (int r = 0; r < 4; ++r)
      out[(brow + qrow + r) * HH + h] = po[nf][r] / lacc[r];
  }
}

extern "C" void kernel_launch(void* const* d_in, const int* in_sizes, int n_in,
                              void* d_out, int out_size, void* d_ws, size_t ws_size,
                              hipStream_t stream) {
  const float* x  = (const float*)d_in[0];
  const float* Wq = (const float*)d_in[1];
  const float* Wk = (const float*)d_in[2];
  const float* Wv = (const float*)d_in[3];
  float* out = (float*)d_out;

  const size_t bth = (size_t)BB * TT * HH;  // 2,097,152
  short* qb  = (short*)d_ws;
  short* kb  = qb + bth;
  short* vtb = kb + bth;
  short* wtb = vtb + bth;  // 192*1024 bf16

  pack_wt<<<96, 256, 0, stream>>>(Wq, Wk, Wv, wtb);
  qkv_mfma<<<(BB * TT) / 64, 256, 0, stream>>>(x, wtb, qb, kb, vtb);
  attn_mfma<<<512, 256, 0, stream>>>(qb, kb, vtb, out);
}

// Round 17
// 79.057 us; speedup vs baseline: 1.8457x; 1.0346x over previous
//
#include <hip/hip_runtime.h>
#include <hip/hip_bf16.h>
#include <math.h>

#define BB 16
#define TT 2048
#define DD 1024
#define HH 64
#define QK_SCALE 0.18033688011112042f  // 0.125 * log2(e)  (exp2-domain softmax)

typedef short bf16x8 __attribute__((ext_vector_type(8)));
typedef short bf16x4 __attribute__((ext_vector_type(4)));
typedef float f32x4 __attribute__((ext_vector_type(4)));

__device__ __forceinline__ short f2bf(float f) {  // RNE (cold paths only)
  union { float f; unsigned u; } c; c.f = f;
  unsigned u = c.u + 0x7FFFu + ((c.u >> 16) & 1u);
  return (short)(u >> 16);
}

// packed pair f32x2 -> bf16x2 (v_cvt_pk_bf16_f32 via standard cast API)
__device__ __forceinline__ unsigned pk2(float lo, float hi) {
  float2 t; t.x = lo; t.y = hi;
  __hip_bfloat162 h = __float22bfloat162_rn(t);
  union { __hip_bfloat162 h; unsigned u; } c; c.h = h;
  return c.u;
}

// Counted-vmcnt fences (T4): newest-N VMEM ops may stay in flight across the
// barrier; everything older is retired. No lgkm drain needed in qkv (no
// ds_write ops; ds_reads are consumed by MFMAs before the barrier).
__device__ __forceinline__ void fence_vm4_barrier() {
  asm volatile("s_waitcnt vmcnt(4)" ::: "memory");
  __builtin_amdgcn_sched_barrier(0);
  __builtin_amdgcn_s_barrier();
}
__device__ __forceinline__ void fence_vm0_barrier() {
  asm volatile("s_waitcnt vmcnt(0)" ::: "memory");
  __builtin_amdgcn_sched_barrier(0);
  __builtin_amdgcn_s_barrier();
}

// 64-col bf16 tile (128B row stride): XOR-swizzle 16B units by row&7.
__device__ __forceinline__ void* lds_swz(void* base, int row, int col) {
  int byte = (row << 7) + (col << 1);
  byte ^= (row & 7) << 4;
  return (void*)((char*)base + byte);
}

// ---------------------------------------------------------------------------
// Pack Wq|Wk|Wv (fp32 [D][H]) -> Wt bf16 [192][1024]
// ---------------------------------------------------------------------------
__global__ __launch_bounds__(256) void pack_wt(
    const float* __restrict__ Wq, const float* __restrict__ Wk,
    const float* __restrict__ Wv, short* __restrict__ wt) {
  const int idx = blockIdx.x * 256 + threadIdx.x;
  const int n = idx >> 7;
  const int k0 = (idx & 127) << 3;
  const float* W = (n < 64) ? Wq : (n < 128) ? Wk : Wv;
  const int h = n & 63;
  bf16x8 o;
#pragma unroll
  for (int j = 0; j < 8; ++j) o[j] = f2bf(W[(k0 + j) * HH + h]);
  *(bf16x8*)&wt[n * DD + k0] = o;
}

// ---------------------------------------------------------------------------
// QKV GEMM v8: global_load_lds (width=16) fp32 staging, 3-buffer rotation,
// counted vmcnt(4) fences (never drain in-loop). Staging is fire-and-forget:
// no VGPR roundtrip, no pack chain on the staging path, no ds_writes.
// LDS layout: linear dest + inverse-swizzled SOURCE (unit u ^= row&7),
// swizzle reapplied on read (rule #21) -> conflict-free fp32 A-frag reads.
// fp32->bf16 conversion happens at A-frag read (4 pk2 per frag).
// W via bcur/bnxt register prefetch as in v2 (proven). Issue order per iter:
// W-loads first, staging second -> fence's "newest 4" = the just-staged tile.
// ---------------------------------------------------------------------------
__global__ __launch_bounds__(256, 2) void qkv_mfma(
    const float* __restrict__ x, const short* __restrict__ wt,
    short* __restrict__ qo, short* __restrict__ ko, short* __restrict__ vt) {
  __shared__ float xls[3][64 * 64];  // 3 x 16 KB fp32 tiles (48 KB)
  const int tid = threadIdx.x;
  const int lane = tid & 63;
  const int w = tid >> 6;
  const int q16 = lane & 15;
  const int g = lane >> 4;
  const size_t r0 = (size_t)blockIdx.x * 64;

  f32x4 acc[4][3];
#pragma unroll
  for (int mf = 0; mf < 4; ++mf)
#pragma unroll
    for (int nf = 0; nf < 3; ++nf) acc[mf][nf] = (f32x4){0.f, 0.f, 0.f, 0.f};

  const short* wp[3];
#pragma unroll
  for (int nf = 0; nf < 3; ++nf)
    wp[nf] = wt + (size_t)(w * 48 + nf * 16 + q16) * DD + g * 8;

  // per-lane staging geometry (4 ops/wave/tile; wave w covers rows w*16..+15)
  const int srow_b = w * 16 + (lane >> 4);  // row for j=0; j adds 4
  const int ul = lane & 15;                 // linear 16B-unit within row

  // ---- prologue: W(k=0) first, then stage tiles 0 and 1 ----
  bf16x8 bcur[3][2];
#pragma unroll
  for (int nf = 0; nf < 3; ++nf)
#pragma unroll
    for (int kf = 0; kf < 2; ++kf)
      bcur[nf][kf] = *(const bf16x8*)(wp[nf] + kf * 32);
#pragma unroll
  for (int t = 0; t < 2; ++t)
#pragma unroll
    for (int j = 0; j < 4; ++j) {
      const int row = srow_b + j * 4;
      const int us = ul ^ (row & 7);
      const float* src = x + (r0 + row) * DD + t * 64 + us * 4;
      __builtin_amdgcn_global_load_lds(
          (const __attribute__((address_space(1))) void*)src,
          (__attribute__((address_space(3))) void*)(&xls[t][0] + (w * 4 + j) * 256),
          16, 0, 0);
    }
  __builtin_amdgcn_sched_barrier(0);
  fence_vm4_barrier();  // tile 0 (and W) retired; tile 1 may stay in flight

  for (int ks = 0; ks < 16; ++ks) {
    const float* bufc = &xls[ks % 3][0];

    // (1) W-frags for NEXT k-step (L2-resident; oldest in-flight group)
    bf16x8 bnxt[3][2];
    if (ks < 15) {
      const int k1 = (ks + 1) << 6;
#pragma unroll
      for (int nf = 0; nf < 3; ++nf)
#pragma unroll
        for (int kf = 0; kf < 2; ++kf)
          bnxt[nf][kf] = *(const bf16x8*)(wp[nf] + k1 + kf * 32);
    }
    // (2) stage tile ks+2 (newest 4 VMEM ops -> survive the fence)
    if (ks < 14) {
#pragma unroll
      for (int j = 0; j < 4; ++j) {
        const int row = srow_b + j * 4;
        const int us = ul ^ (row & 7);
        const float* src = x + (r0 + row) * DD + (ks + 2) * 64 + us * 4;
        __builtin_amdgcn_global_load_lds(
            (const __attribute__((address_space(1))) void*)src,
            (__attribute__((address_space(3))) void*)(&xls[(ks + 2) % 3][0] +
                                                      (w * 4 + j) * 256),
            16, 0, 0);
      }
    }
    __builtin_amdgcn_sched_barrier(0);  // pin issue order before compute

    // (3) A-frags: fp32 from LDS (swizzled units), cvt_pk -> bf16
    bf16x8 afr[4][2];
#pragma unroll
    for (int mf = 0; mf < 4; ++mf)
#pragma unroll
      for (int kf = 0; kf < 2; ++kf) {
        const int R = mf * 16 + q16;
        const int r7 = R & 7;
        const int u0 = kf * 8 + g * 2;
        const float4 fa = *(const float4*)(bufc + R * 64 + ((u0 ^ r7) << 2));
        const float4 fb = *(const float4*)(bufc + R * 64 + (((u0 + 1) ^ r7) << 2));
        unsigned* up = (unsigned*)&afr[mf][kf];
        up[0] = pk2(fa.x, fa.y);
        up[1] = pk2(fa.z, fa.w);
        up[2] = pk2(fb.x, fb.y);
        up[3] = pk2(fb.z, fb.w);
      }

    // (4) MFMA burst
#pragma unroll
    for (int mf = 0; mf < 4; ++mf)
#pragma unroll
      for (int nf = 0; nf < 3; ++nf)
#pragma unroll
        for (int kf = 0; kf < 2; ++kf)
          acc[mf][nf] = __builtin_amdgcn_mfma_f32_16x16x32_bf16(
              afr[mf][kf], bcur[nf][kf], acc[mf][nf], 0, 0, 0);

    // (5) counted fence: tile ks+1 ready; tile ks+2 stays in flight
    if (ks < 15) {
      if (ks < 14) fence_vm4_barrier(); else fence_vm0_barrier();
#pragma unroll
      for (int nf = 0; nf < 3; ++nf)
#pragma unroll
        for (int kf = 0; kf < 2; ++kf) bcur[nf][kf] = bnxt[nf][kf];
    }
  }

  // epilogue: q/k row-major bf16 (Q pre-scaled); v transposed to vt [b][h][t]
#pragma unroll
  for (int nf = 0; nf < 3; ++nf) {
    const int n = w * 48 + nf * 16 + q16;
    const int mat = n >> 6;  // frag-uniform
    const int h = n & 63;
    if (mat < 2) {
      short* outp = mat ? ko : qo;
      const float fac = mat ? 1.0f : QK_SCALE;
#pragma unroll
      for (int mf = 0; mf < 4; ++mf)
#pragma unroll
        for (int r = 0; r < 4; ++r)
          outp[(r0 + mf * 16 + g * 4 + r) * HH + h] = f2bf(acc[mf][nf][r] * fac);
    } else {
      const int bb = (int)(r0 >> 11);
      const int tloc = (int)(r0 & 2047);
#pragma unroll
      for (int mf = 0; mf < 4; ++mf) {
        uint2 pkv;
        pkv.x = pk2(acc[mf][nf][0], acc[mf][nf][1]);
        pkv.y = pk2(acc[mf][nf][2], acc[mf][nf][3]);
        *(uint2*)&vt[((size_t)bb * HH + h) * TT + tloc + mf * 16 + g * 4] = pkv;
      }
    }
  }
}

// ---------------------------------------------------------------------------
// Flash attention (identical to round 10 structure — best measured).
// ---------------------------------------------------------------------------
__global__ __launch_bounds__(256, 4) void attn_mfma(
    const short* __restrict__ q, const short* __restrict__ k,
    const short* __restrict__ vt, float* __restrict__ out) {
  __shared__ short klds[2][64 * 64];
  __shared__ short vlds[2][64 * 64];

  const int id = blockIdx.x;  // 0..511
  const int b = (id & 7) | (((id >> 3) & 1) << 3);
  const int kk = id >> 4;
  const int qt = (kk < 16) ? (31 - kk) : (kk - 16);
  const int t0 = qt << 6;
  const int tid = threadIdx.x;
  const int lane = tid & 63;
  const int w = tid >> 6;
  const int q16 = lane & 15;
  const int g = lane >> 4;
  const int NC = qt + 1;

  const size_t brow = (size_t)b * TT;
  const short* kg = k + brow * HH;
  const short* vtg = vt + (size_t)b * HH * TT;

  const int srow = tid >> 2;
  const int scol = (tid & 3) << 4;

  const int vgA = (scol >> 3) & 3;
  const int vgB = ((scol + 8) >> 3) & 3;
  const int vm2 = scol >> 5;
  const short* vrow_p = vtg + srow * TT + vm2 * 32;

  bf16x8 kr0 = *(const bf16x8*)&kg[srow * HH + scol];
  bf16x8 kr1 = *(const bf16x8*)&kg[srow * HH + scol + 8];
  bf16x4 va0 = *(const bf16x4*)(vrow_p + 4 * vgA);
  bf16x4 va1 = *(const bf16x4*)(vrow_p + 16 + 4 * vgA);
  bf16x4 vb0 = *(const bf16x4*)(vrow_p + 4 * vgB);
  bf16x4 vb1 = *(const bf16x4*)(vrow_p + 16 + 4 * vgB);

  {
    const short* qsrc = q + (brow + t0 + srow) * HH;
    *(bf16x8*)lds_swz(klds[0], srow, scol) = *(const bf16x8*)&qsrc[scol];
    *(bf16x8*)lds_swz(klds[0], srow, scol + 8) = *(const bf16x8*)&qsrc[scol + 8];
  }
  __syncthreads();
  bf16x8 qa[2];
#pragma unroll
  for (int kf = 0; kf < 2; ++kf)
    qa[kf] = *(bf16x8*)lds_swz(klds[0], w * 16 + q16, kf * 32 + g * 8);
  __syncthreads();

  *(bf16x8*)lds_swz(klds[0], srow, scol) = kr0;
  *(bf16x8*)lds_swz(klds[0], srow, scol + 8) = kr1;
  *(bf16x8*)lds_swz(vlds[0], srow, scol) =
      __builtin_shufflevector(va0, va1, 0, 1, 2, 3, 4, 5, 6, 7);
  *(bf16x8*)lds_swz(vlds[0], srow, scol + 8) =
      __builtin_shufflevector(vb0, vb1, 0, 1, 2, 3, 4, 5, 6, 7);
  __syncthreads();

  f32x4 po[4];
  f32x4 lacc = (f32x4){0.f, 0.f, 0.f, 0.f};
  float m = -INFINITY;
#pragma unroll
  for (int nf = 0; nf < 4; ++nf) po[nf] = (f32x4){0.f, 0.f, 0.f, 0.f};

  const bf16x8 ones = {0x3F80, 0x3F80, 0x3F80, 0x3F80,
                       0x3F80, 0x3F80, 0x3F80, 0x3F80};
  int cur = 0;

  for (int c = 0; c < NC; ++c) {
    const bool notlast = (c + 1 < NC);
    if (notlast) {
      const int s1 = (c + 1) << 6;
      kr0 = *(const bf16x8*)&kg[(s1 + srow) * HH + scol];
      kr1 = *(const bf16x8*)&kg[(s1 + srow) * HH + scol + 8];
      va0 = *(const bf16x4*)(vrow_p + s1 + 4 * vgA);
      va1 = *(const bf16x4*)(vrow_p + s1 + 16 + 4 * vgA);
      vb0 = *(const bf16x4*)(vrow_p + s1 + 4 * vgB);
      vb1 = *(const bf16x4*)(vrow_p + s1 + 16 + 4 * vgB);
    }

    f32x4 sfr[4];
#pragma unroll
    for (int nf = 0; nf < 4; ++nf) sfr[nf] = (f32x4){0.f, 0.f, 0.f, 0.f};
    __builtin_amdgcn_s_setprio(1);
#pragma unroll
    for (int nf = 0; nf < 4; ++nf)
#pragma unroll
      for (int kf = 0; kf < 2; ++kf) {
        bf16x8 kb = *(bf16x8*)lds_swz(klds[cur], nf * 16 + q16, kf * 32 + g * 8);
        sfr[nf] = __builtin_amdgcn_mfma_f32_16x16x32_bf16(kb, qa[kf], sfr[nf], 0, 0, 0);
      }
    __builtin_amdgcn_s_setprio(0);

    if (c == NC - 1) {
      const int qloc = w * 16 + q16;
#pragma unroll
      for (int nf = 0; nf < 4; ++nf)
#pragma unroll
        for (int r = 0; r < 4; ++r)
          if (16 * nf + 4 * g + r > qloc) sfr[nf][r] = -INFINITY;
    }

    float pm;
    {
      f32x4 t01 = (f32x4){fmaxf(sfr[0][0], sfr[1][0]), fmaxf(sfr[0][1], sfr[1][1]),
                          fmaxf(sfr[0][2], sfr[1][2]), fmaxf(sfr[0][3], sfr[1][3])};
      f32x4 t23 = (f32x4){fmaxf(sfr[2][0], sfr[3][0]), fmaxf(sfr[2][1], sfr[3][1]),
                          fmaxf(sfr[2][2], sfr[3][2]), fmaxf(sfr[2][3], sfr[3][3])};
      pm = fmaxf(fmaxf(fmaxf(t01[0], t23[0]), fmaxf(t01[1], t23[1])),
                 fmaxf(fmaxf(t01[2], t23[2]), fmaxf(t01[3], t23[3])));
      pm = fmaxf(pm, __shfl_xor(pm, 16));
      pm = fmaxf(pm, __shfl_xor(pm, 32));
    }

    if (__any(pm - m > 8.f)) {
      const float mn = fmaxf(m, pm);
      const float corr = exp2f(m - mn);
      m = mn;
      const int sbase = (lane & 48) + ((lane >> 4) << 2);
#pragma unroll
      for (int r = 0; r < 4; ++r) {
        const float cr = __shfl(corr, sbase + r);
        lacc[r] *= cr;
#pragma unroll
        for (int nf = 0; nf < 4; ++nf) po[nf][r] *= cr;
      }
    }

    bf16x8 pa[2];
#pragma unroll
    for (int m2 = 0; m2 < 2; ++m2) {
      float e0 = exp2f(sfr[2 * m2][0] - m), e1 = exp2f(sfr[2 * m2][1] - m);
      float e2 = exp2f(sfr[2 * m2][2] - m), e3 = exp2f(sfr[2 * m2][3] - m);
      float e4 = exp2f(sfr[2 * m2 + 1][0] - m), e5 = exp2f(sfr[2 * m2 + 1][1] - m);
      float e6 = exp2f(sfr[2 * m2 + 1][2] - m), e7 = exp2f(sfr[2 * m2 + 1][3] - m);
      unsigned* up = (unsigned*)&pa[m2];
      up[0] = pk2(e0, e1); up[1] = pk2(e2, e3);
      up[2] = pk2(e4, e5); up[3] = pk2(e6, e7);
    }

    __builtin_amdgcn_s_setprio(1);
#pragma unroll
    for (int m2 = 0; m2 < 2; ++m2) {
#pragma unroll
      for (int nf = 0; nf < 4; ++nf) {
        bf16x8 vb = *(bf16x8*)lds_swz(vlds[cur], nf * 16 + q16, m2 * 32 + g * 8);
        po[nf] = __builtin_amdgcn_mfma_f32_16x16x32_bf16(pa[m2], vb, po[nf], 0, 0, 0);
      }
      lacc = __builtin_amdgcn_mfma_f32_16x16x32_bf16(pa[m2], ones, lacc, 0, 0, 0);
    }
    __builtin_amdgcn_s_setprio(0);

    if (notlast) {
      *(bf16x8*)lds_swz(klds[cur ^ 1], srow, scol) = kr0;
      *(bf16x8*)lds_swz(klds[cur ^ 1], srow, scol + 8) = kr1;
      *(bf16x8*)lds_swz(vlds[cur ^ 1], srow, scol) =
          __builtin_shufflevector(va0, va1, 0, 1, 2, 3, 4, 5, 6, 7);
      *(bf16x8*)lds_swz(vlds[cur ^ 1], srow, scol + 8) =
          __builtin_shufflevector(vb0, vb1, 0, 1, 2, 3, 4, 5, 6, 7);
      __syncthreads();
      cur ^= 1;
    }
  }

  const int qrow = t0 + w * 16 + g * 4;
#pragma unroll
  for (int nf = 0; nf < 4; ++nf) {
    const int h = nf * 16 + q16;
#pragma unroll
    for (int r = 0; r < 4; ++r)
      out[(brow + qrow + r) * HH + h] = po[nf][r] / lacc[r];
  }
}

extern "C" void kernel_launch(void* const* d_in, const int* in_sizes, int n_in,
                              void* d_out, int out_size, void* d_ws, size_t ws_size,
                              hipStream_t stream) {
  const float* x  = (const float*)d_in[0];
  const float* Wq = (const float*)d_in[1];
  const float* Wk = (const float*)d_in[2];
  const float* Wv = (const float*)d_in[3];
  float* out = (float*)d_out;

  const size_t bth = (size_t)BB * TT * HH;  // 2,097,152
  short* qb  = (short*)d_ws;
  short* kb  = qb + bth;
  short* vtb = kb + bth;
  short* wtb = vtb + bth;  // 192*1024 bf16

  pack_wt<<<96, 256, 0, stream>>>(Wq, Wk, Wv, wtb);
  qkv_mfma<<<(BB * TT) / 64, 256, 0, stream>>>(x, wtb, qb, kb, vtb);
  attn_mfma<<<512, 256, 0, stream>>>(qb, kb, vtb, out);
}

// Round 18
// 78.837 us; speedup vs baseline: 1.8509x; 1.0028x over previous
//
#include <hip/hip_runtime.h>
#include <hip/hip_bf16.h>
#include <math.h>

#define BB 16
#define TT 2048
#define DD 1024
#define HH 64
#define QK_SCALE 0.18033688011112042f  // 0.125 * log2(e)  (exp2-domain softmax)

typedef short bf16x8 __attribute__((ext_vector_type(8)));
typedef short bf16x4 __attribute__((ext_vector_type(4)));
typedef float f32x4 __attribute__((ext_vector_type(4)));

__device__ __forceinline__ short f2bf(float f) {  // RNE (cold paths only)
  union { float f; unsigned u; } c; c.f = f;
  unsigned u = c.u + 0x7FFFu + ((c.u >> 16) & 1u);
  return (short)(u >> 16);
}

// packed pair f32x2 -> bf16x2 (v_cvt_pk_bf16_f32 via standard cast API)
__device__ __forceinline__ unsigned pk2(float lo, float hi) {
  float2 t; t.x = lo; t.y = hi;
  __hip_bfloat162 h = __float22bfloat162_rn(t);
  union { __hip_bfloat162 h; unsigned u; } c; c.h = h;
  return c.u;
}

// Counted-vmcnt fences (T4): newest-N VMEM ops stay in flight across the
// barrier; everything older is retired before any wave proceeds.
#define FENCE_VM(N)                                        \
  do {                                                     \
    asm volatile("s_waitcnt vmcnt(" #N ")" ::: "memory");  \
    __builtin_amdgcn_sched_barrier(0);                     \
    __builtin_amdgcn_s_barrier();                          \
  } while (0)

// 64-col bf16 tile (128B row stride): XOR-swizzle 16B units by row&7.
__device__ __forceinline__ void* lds_swz(void* base, int row, int col) {
  int byte = (row << 7) + (col << 1);
  byte ^= (row & 7) << 4;
  return (void*)((char*)base + byte);
}

// ---------------------------------------------------------------------------
// Pack Wq|Wk|Wv (fp32 [D][H]) -> Wt bf16 [192][1024]
// ---------------------------------------------------------------------------
__global__ __launch_bounds__(256) void pack_wt(
    const float* __restrict__ Wq, const float* __restrict__ Wk,
    const float* __restrict__ Wv, short* __restrict__ wt) {
  const int idx = blockIdx.x * 256 + threadIdx.x;
  const int n = idx >> 7;
  const int k0 = (idx & 127) << 3;
  const float* W = (n < 64) ? Wq : (n < 128) ? Wk : Wv;
  const int h = n & 63;
  bf16x8 o;
#pragma unroll
  for (int j = 0; j < 8; ++j) o[j] = f2bf(W[(k0 + j) * HH + h]);
  *(bf16x8*)&wt[n * DD + k0] = o;
}

// ---------------------------------------------------------------------------
// QKV GEMM v9: v8 (global_load_lds fp32 staging) with DEPTH-3 pipeline.
// 4-buffer rotation; iter ks stages tile ks+3; end-of-iter fence keeps 14
// VMEM ops in flight (stage ks+3 [4] + W ks+1 [6] + stage ks+2 [4]) so tile
// ks+1's loads get ~2.3 iterations (~1000cy) of latency cover. Tail fences
// 10 / 6. Linear LDS dest + inverse-swizzled global source, swizzle on read.
// ---------------------------------------------------------------------------
__global__ __launch_bounds__(256, 2) void qkv_mfma(
    const float* __restrict__ x, const short* __restrict__ wt,
    short* __restrict__ qo, short* __restrict__ ko, short* __restrict__ vt) {
  __shared__ float xls[4][64 * 64];  // 4 x 16 KB fp32 tiles (64 KB)
  const int tid = threadIdx.x;
  const int lane = tid & 63;
  const int w = tid >> 6;
  const int q16 = lane & 15;
  const int g = lane >> 4;
  const size_t r0 = (size_t)blockIdx.x * 64;

  f32x4 acc[4][3];
#pragma unroll
  for (int mf = 0; mf < 4; ++mf)
#pragma unroll
    for (int nf = 0; nf < 3; ++nf) acc[mf][nf] = (f32x4){0.f, 0.f, 0.f, 0.f};

  const short* wp[3];
#pragma unroll
  for (int nf = 0; nf < 3; ++nf)
    wp[nf] = wt + (size_t)(w * 48 + nf * 16 + q16) * DD + g * 8;

  // per-lane staging geometry (4 ops/wave/tile; wave w covers rows w*16..+15)
  const int srow_b = w * 16 + (lane >> 4);  // row for j=0; j adds 4
  const int ul = lane & 15;                 // linear 16B-unit within row

  // ---- prologue: W(k=0) first, then stage tiles 0,1,2 ----
  bf16x8 bcur[3][2];
#pragma unroll
  for (int nf = 0; nf < 3; ++nf)
#pragma unroll
    for (int kf = 0; kf < 2; ++kf)
      bcur[nf][kf] = *(const bf16x8*)(wp[nf] + kf * 32);
#pragma unroll
  for (int t = 0; t < 3; ++t)
#pragma unroll
    for (int j = 0; j < 4; ++j) {
      const int row = srow_b + j * 4;
      const int us = ul ^ (row & 7);
      const float* src = x + (r0 + row) * DD + t * 64 + us * 4;
      __builtin_amdgcn_global_load_lds(
          (const __attribute__((address_space(1))) void*)src,
          (__attribute__((address_space(3))) void*)(&xls[t][0] + (w * 4 + j) * 256),
          16, 0, 0);
    }
  __builtin_amdgcn_sched_barrier(0);
  FENCE_VM(8);  // W + tile 0 retired; tiles 1,2 stay in flight

  for (int ks = 0; ks < 16; ++ks) {
    const float* bufc = &xls[ks & 3][0];

    // (1) W-frags for NEXT k-step (L2-resident)
    bf16x8 bnxt[3][2];
    if (ks < 15) {
      const int k1 = (ks + 1) << 6;
#pragma unroll
      for (int nf = 0; nf < 3; ++nf)
#pragma unroll
        for (int kf = 0; kf < 2; ++kf)
          bnxt[nf][kf] = *(const bf16x8*)(wp[nf] + k1 + kf * 32);
    }
    // (2) stage tile ks+3 (newest ops -> survive the fence)
    if (ks <= 12) {
#pragma unroll
      for (int j = 0; j < 4; ++j) {
        const int row = srow_b + j * 4;
        const int us = ul ^ (row & 7);
        const float* src = x + (r0 + row) * DD + (ks + 3) * 64 + us * 4;
        __builtin_amdgcn_global_load_lds(
            (const __attribute__((address_space(1))) void*)src,
            (__attribute__((address_space(3))) void*)(&xls[(ks + 3) & 3][0] +
                                                      (w * 4 + j) * 256),
            16, 0, 0);
      }
    }
    __builtin_amdgcn_sched_barrier(0);  // pin issue order before compute

    // (3) A-frags: fp32 from LDS (swizzled units), cvt_pk -> bf16
    bf16x8 afr[4][2];
#pragma unroll
    for (int mf = 0; mf < 4; ++mf)
#pragma unroll
      for (int kf = 0; kf < 2; ++kf) {
        const int R = mf * 16 + q16;
        const int r7 = R & 7;
        const int u0 = kf * 8 + g * 2;
        const float4 fa = *(const float4*)(bufc + R * 64 + ((u0 ^ r7) << 2));
        const float4 fb = *(const float4*)(bufc + R * 64 + (((u0 + 1) ^ r7) << 2));
        unsigned* up = (unsigned*)&afr[mf][kf];
        up[0] = pk2(fa.x, fa.y);
        up[1] = pk2(fa.z, fa.w);
        up[2] = pk2(fb.x, fb.y);
        up[3] = pk2(fb.z, fb.w);
      }

    // (4) MFMA burst
#pragma unroll
    for (int mf = 0; mf < 4; ++mf)
#pragma unroll
      for (int nf = 0; nf < 3; ++nf)
#pragma unroll
        for (int kf = 0; kf < 2; ++kf)
          acc[mf][nf] = __builtin_amdgcn_mfma_f32_16x16x32_bf16(
              afr[mf][kf], bcur[nf][kf], acc[mf][nf], 0, 0, 0);

    // (5) counted fence: tile ks+1 ready; ks+2, ks+3 stay in flight
    if (ks < 15) {
      if (ks <= 12) FENCE_VM(14);
      else if (ks == 13) FENCE_VM(10);
      else FENCE_VM(6);
#pragma unroll
      for (int nf = 0; nf < 3; ++nf)
#pragma unroll
        for (int kf = 0; kf < 2; ++kf) bcur[nf][kf] = bnxt[nf][kf];
    }
  }

  // epilogue: q/k row-major bf16 (Q pre-scaled); v transposed to vt [b][h][t]
#pragma unroll
  for (int nf = 0; nf < 3; ++nf) {
    const int n = w * 48 + nf * 16 + q16;
    const int mat = n >> 6;  // frag-uniform
    const int h = n & 63;
    if (mat < 2) {
      short* outp = mat ? ko : qo;
      const float fac = mat ? 1.0f : QK_SCALE;
#pragma unroll
      for (int mf = 0; mf < 4; ++mf)
#pragma unroll
        for (int r = 0; r < 4; ++r)
          outp[(r0 + mf * 16 + g * 4 + r) * HH + h] = f2bf(acc[mf][nf][r] * fac);
    } else {
      const int bb = (int)(r0 >> 11);
      const int tloc = (int)(r0 & 2047);
#pragma unroll
      for (int mf = 0; mf < 4; ++mf) {
        uint2 pkv;
        pkv.x = pk2(acc[mf][nf][0], acc[mf][nf][1]);
        pkv.y = pk2(acc[mf][nf][2], acc[mf][nf][3]);
        *(uint2*)&vt[((size_t)bb * HH + h) * TT + tloc + mf * 16 + g * 4] = pkv;
      }
    }
  }
}

// ---------------------------------------------------------------------------
// Flash attention (identical to round 10 structure — best measured).
// ---------------------------------------------------------------------------
__global__ __launch_bounds__(256, 4) void attn_mfma(
    const short* __restrict__ q, const short* __restrict__ k,
    const short* __restrict__ vt, float* __restrict__ out) {
  __shared__ short klds[2][64 * 64];
  __shared__ short vlds[2][64 * 64];

  const int id = blockIdx.x;  // 0..511
  const int b = (id & 7) | (((id >> 3) & 1) << 3);
  const int kk = id >> 4;
  const int qt = (kk < 16) ? (31 - kk) : (kk - 16);
  const int t0 = qt << 6;
  const int tid = threadIdx.x;
  const int lane = tid & 63;
  const int w = tid >> 6;
  const int q16 = lane & 15;
  const int g = lane >> 4;
  const int NC = qt + 1;

  const size_t brow = (size_t)b * TT;
  const short* kg = k + brow * HH;
  const short* vtg = vt + (size_t)b * HH * TT;

  const int srow = tid >> 2;
  const int scol = (tid & 3) << 4;

  const int vgA = (scol >> 3) & 3;
  const int vgB = ((scol + 8) >> 3) & 3;
  const int vm2 = scol >> 5;
  const short* vrow_p = vtg + srow * TT + vm2 * 32;

  bf16x8 kr0 = *(const bf16x8*)&kg[srow * HH + scol];
  bf16x8 kr1 = *(const bf16x8*)&kg[srow * HH + scol + 8];
  bf16x4 va0 = *(const bf16x4*)(vrow_p + 4 * vgA);
  bf16x4 va1 = *(const bf16x4*)(vrow_p + 16 + 4 * vgA);
  bf16x4 vb0 = *(const bf16x4*)(vrow_p + 4 * vgB);
  bf16x4 vb1 = *(const bf16x4*)(vrow_p + 16 + 4 * vgB);

  {
    const short* qsrc = q + (brow + t0 + srow) * HH;
    *(bf16x8*)lds_swz(klds[0], srow, scol) = *(const bf16x8*)&qsrc[scol];
    *(bf16x8*)lds_swz(klds[0], srow, scol + 8) = *(const bf16x8*)&qsrc[scol + 8];
  }
  __syncthreads();
  bf16x8 qa[2];
#pragma unroll
  for (int kf = 0; kf < 2; ++kf)
    qa[kf] = *(bf16x8*)lds_swz(klds[0], w * 16 + q16, kf * 32 + g * 8);
  __syncthreads();

  *(bf16x8*)lds_swz(klds[0], srow, scol) = kr0;
  *(bf16x8*)lds_swz(klds[0], srow, scol + 8) = kr1;
  *(bf16x8*)lds_swz(vlds[0], srow, scol) =
      __builtin_shufflevector(va0, va1, 0, 1, 2, 3, 4, 5, 6, 7);
  *(bf16x8*)lds_swz(vlds[0], srow, scol + 8) =
      __builtin_shufflevector(vb0, vb1, 0, 1, 2, 3, 4, 5, 6, 7);
  __syncthreads();

  f32x4 po[4];
  f32x4 lacc = (f32x4){0.f, 0.f, 0.f, 0.f};
  float m = -INFINITY;
#pragma unroll
  for (int nf = 0; nf < 4; ++nf) po[nf] = (f32x4){0.f, 0.f, 0.f, 0.f};

  const bf16x8 ones = {0x3F80, 0x3F80, 0x3F80, 0x3F80,
                       0x3F80, 0x3F80, 0x3F80, 0x3F80};
  int cur = 0;

  for (int c = 0; c < NC; ++c) {
    const bool notlast = (c + 1 < NC);
    if (notlast) {
      const int s1 = (c + 1) << 6;
      kr0 = *(const bf16x8*)&kg[(s1 + srow) * HH + scol];
      kr1 = *(const bf16x8*)&kg[(s1 + srow) * HH + scol + 8];
      va0 = *(const bf16x4*)(vrow_p + s1 + 4 * vgA);
      va1 = *(const bf16x4*)(vrow_p + s1 + 16 + 4 * vgA);
      vb0 = *(const bf16x4*)(vrow_p + s1 + 4 * vgB);
      vb1 = *(const bf16x4*)(vrow_p + s1 + 16 + 4 * vgB);
    }

    f32x4 sfr[4];
#pragma unroll
    for (int nf = 0; nf < 4; ++nf) sfr[nf] = (f32x4){0.f, 0.f, 0.f, 0.f};
    __builtin_amdgcn_s_setprio(1);
#pragma unroll
    for (int nf = 0; nf < 4; ++nf)
#pragma unroll
      for (int kf = 0; kf < 2; ++kf) {
        bf16x8 kb = *(bf16x8*)lds_swz(klds[cur], nf * 16 + q16, kf * 32 + g * 8);
        sfr[nf] = __builtin_amdgcn_mfma_f32_16x16x32_bf16(kb, qa[kf], sfr[nf], 0, 0, 0);
      }
    __builtin_amdgcn_s_setprio(0);

    if (c == NC - 1) {
      const int qloc = w * 16 + q16;
#pragma unroll
      for (int nf = 0; nf < 4; ++nf)
#pragma unroll
        for (int r = 0; r < 4; ++r)
          if (16 * nf + 4 * g + r > qloc) sfr[nf][r] = -INFINITY;
    }

    float pm;
    {
      f32x4 t01 = (f32x4){fmaxf(sfr[0][0], sfr[1][0]), fmaxf(sfr[0][1], sfr[1][1]),
                          fmaxf(sfr[0][2], sfr[1][2]), fmaxf(sfr[0][3], sfr[1][3])};
      f32x4 t23 = (f32x4){fmaxf(sfr[2][0], sfr[3][0]), fmaxf(sfr[2][1], sfr[3][1]),
                          fmaxf(sfr[2][2], sfr[3][2]), fmaxf(sfr[2][3], sfr[3][3])};
      pm = fmaxf(fmaxf(fmaxf(t01[0], t23[0]), fmaxf(t01[1], t23[1])),
                 fmaxf(fmaxf(t01[2], t23[2]), fmaxf(t01[3], t23[3])));
      pm = fmaxf(pm, __shfl_xor(pm, 16));
      pm = fmaxf(pm, __shfl_xor(pm, 32));
    }

    if (__any(pm - m > 8.f)) {
      const float mn = fmaxf(m, pm);
      const float corr = exp2f(m - mn);
      m = mn;
      const int sbase = (lane & 48) + ((lane >> 4) << 2);
#pragma unroll
      for (int r = 0; r < 4; ++r) {
        const float cr = __shfl(corr, sbase + r);
        lacc[r] *= cr;
#pragma unroll
        for (int nf = 0; nf < 4; ++nf) po[nf][r] *= cr;
      }
    }

    bf16x8 pa[2];
#pragma unroll
    for (int m2 = 0; m2 < 2; ++m2) {
      float e0 = exp2f(sfr[2 * m2][0] - m), e1 = exp2f(sfr[2 * m2][1] - m);
      float e2 = exp2f(sfr[2 * m2][2] - m), e3 = exp2f(sfr[2 * m2][3] - m);
      float e4 = exp2f(sfr[2 * m2 + 1][0] - m), e5 = exp2f(sfr[2 * m2 + 1][1] - m);
      float e6 = exp2f(sfr[2 * m2 + 1][2] - m), e7 = exp2f(sfr[2 * m2 + 1][3] - m);
      unsigned* up = (unsigned*)&pa[m2];
      up[0] = pk2(e0, e1); up[1] = pk2(e2, e3);
      up[2] = pk2(e4, e5); up[3] = pk2(e6, e7);
    }

    __builtin_amdgcn_s_setprio(1);
#pragma unroll
    for (int m2 = 0; m2 < 2; ++m2) {
#pragma unroll
      for (int nf = 0; nf < 4; ++nf) {
        bf16x8 vb = *(bf16x8*)lds_swz(vlds[cur], nf * 16 + q16, m2 * 32 + g * 8);
        po[nf] = __builtin_amdgcn_mfma_f32_16x16x32_bf16(pa[m2], vb, po[nf], 0, 0, 0);
      }
      lacc = __builtin_amdgcn_mfma_f32_16x16x32_bf16(pa[m2], ones, lacc, 0, 0, 0);
    }
    __builtin_amdgcn_s_setprio(0);

    if (notlast) {
      *(bf16x8*)lds_swz(klds[cur ^ 1], srow, scol) = kr0;
      *(bf16x8*)lds_swz(klds[cur ^ 1], srow, scol + 8) = kr1;
      *(bf16x8*)lds_swz(vlds[cur ^ 1], srow, scol) =
          __builtin_shufflevector(va0, va1, 0, 1, 2, 3, 4, 5, 6, 7);
      *(bf16x8*)lds_swz(vlds[cur ^ 1], srow, scol + 8) =
          __builtin_shufflevector(vb0, vb1, 0, 1, 2, 3, 4, 5, 6, 7);
      __syncthreads();
      cur ^= 1;
    }
  }

  const int qrow = t0 + w * 16 + g * 4;
#pragma unroll
  for (int nf = 0; nf < 4; ++nf) {
    const int h = nf * 16 + q16;
#pragma unroll
    for (int r = 0; r < 4; ++r)
      out[(brow + qrow + r) * HH + h] = po[nf][r] / lacc[r];
  }
}

extern "C" void kernel_launch(void* const* d_in, const int* in_sizes, int n_in,
                              void* d_out, int out_size, void* d_ws, size_t ws_size,
                              hipStream_t stream) {
  const float* x  = (const float*)d_in[0];
  const float* Wq = (const float*)d_in[1];
  const float* Wk = (const float*)d_in[2];
  const float* Wv = (const float*)d_in[3];
  float* out = (float*)d_out;

  const size_t bth = (size_t)BB * TT * HH;  // 2,097,152
  short* qb  = (short*)d_ws;
  short* kb  = qb + bth;
  short* vtb = kb + bth;
  short* wtb = vtb + bth;  // 192*1024 bf16

  pack_wt<<<96, 256, 0, stream>>>(Wq, Wk, Wv, wtb);
  qkv_mfma<<<(BB * TT) / 64, 256, 0, stream>>>(x, wtb, qb, kb, vtb);
  attn_mfma<<<512, 256, 0, stream>>>(qb, kb, vtb, out);
}